// Round 1
// baseline (1383.979 us; speedup 1.0000x reference)
//
#include <hip/hip_runtime.h>
#include <cstdint>
#include <cstddef>

#define N_V   8192
#define F_INN 512
#define F_OUT 64
#define CC    4
#define KSEL  16
#define CAP   256
#define THRESH 2.5f

// ---------------- Kernel 1: h = x @ W  (fp32, vector ALU) ----------------
// 16 rows per block, 256 threads. x rows staged in LDS (broadcast reads),
// W column reads are coalesced and L2-hot (W = 128 KB).
__global__ __launch_bounds__(256) void linear_kernel(const float* __restrict__ x,
                                                     const float* __restrict__ W,
                                                     float* __restrict__ h) {
    __shared__ float sx[16 * F_INN];
    const int tid  = threadIdx.x;
    const int row0 = blockIdx.x * 16;

    const float4* x4  = (const float4*)(x + (size_t)row0 * F_INN);
    float4*       sx4 = (float4*)sx;
#pragma unroll
    for (int i = 0; i < 8; ++i) sx4[i * 256 + tid] = x4[i * 256 + tid];
    __syncthreads();

    const int f  = tid & 63;
    const int rg = tid >> 6;  // wave id 0..3 -> rows rg*4 .. rg*4+3
    float acc0 = 0.f, acc1 = 0.f, acc2 = 0.f, acc3 = 0.f;
#pragma unroll 4
    for (int k = 0; k < F_INN; ++k) {
        const float wv = W[k * F_OUT + f];
        acc0 += sx[(rg * 4 + 0) * F_INN + k] * wv;
        acc1 += sx[(rg * 4 + 1) * F_INN + k] * wv;
        acc2 += sx[(rg * 4 + 2) * F_INN + k] * wv;
        acc3 += sx[(rg * 4 + 3) * F_INN + k] * wv;
    }
    float* hp = h + (size_t)(row0 + rg * 4) * F_OUT + f;
    hp[0 * F_OUT] = acc0;
    hp[1 * F_OUT] = acc1;
    hp[2 * F_OUT] = acc2;
    hp[3 * F_OUT] = acc3;
}

// Sortable key: higher value wins; tie -> smaller index wins (matches lax.top_k).
__device__ __forceinline__ unsigned long long make_key(float v, int idx) {
    unsigned u = __float_as_uint(v);
    u = (u & 0x80000000u) ? ~u : (u | 0x80000000u);
    return ((unsigned long long)u << 32) | (unsigned long long)(0xFFFFFFFFu - (unsigned)idx);
}

// ---------------- Kernel 2: per-row top-16 + softmax + weighted gather ----------------
// One block (256 threads) per row r of attention [N*C, N].
__global__ __launch_bounds__(256) void topk_spmm_kernel(const float* __restrict__ att,
                                                        const float* __restrict__ h,
                                                        float* __restrict__ out) {
    __shared__ int   s_cnt;
    __shared__ float s_val[CAP];
    __shared__ int   s_idx[CAP];
    __shared__ int   s_sel_idx[KSEL];
    __shared__ float s_sel_v[KSEL];
    __shared__ float s_sel_e[KSEL];
    __shared__ float s_part[4][F_OUT];
    __shared__ unsigned long long s_red[256];
    __shared__ unsigned long long s_bound;

    const int tid = threadIdx.x;
    const int r   = blockIdx.x;
    const float4* att4 = (const float4*)(att + (size_t)r * N_V);

    if (tid == 0) s_cnt = 0;
    __syncthreads();

    // Stream the whole row: 8 x float4 per thread, all loads issued up front.
    float4 v[8];
#pragma unroll
    for (int j = 0; j < 8; ++j) v[j] = att4[j * 256 + tid];

#pragma unroll
    for (int j = 0; j < 8; ++j) {
        const int base = (j * 256 + tid) * 4;
        if (v[j].x > THRESH) { int p = atomicAdd(&s_cnt, 1); if (p < CAP) { s_val[p] = v[j].x; s_idx[p] = base + 0; } }
        if (v[j].y > THRESH) { int p = atomicAdd(&s_cnt, 1); if (p < CAP) { s_val[p] = v[j].y; s_idx[p] = base + 1; } }
        if (v[j].z > THRESH) { int p = atomicAdd(&s_cnt, 1); if (p < CAP) { s_val[p] = v[j].z; s_idx[p] = base + 2; } }
        if (v[j].w > THRESH) { int p = atomicAdd(&s_cnt, 1); if (p < CAP) { s_val[p] = v[j].w; s_idx[p] = base + 3; } }
    }
    __syncthreads();
    const int cnt = s_cnt;  // uniform across block

    if (cnt >= KSEL && cnt <= CAP) {
        // Exact rank of each candidate (strict total order via (val desc, idx asc)).
        if (tid < cnt) {
            const float myv = s_val[tid];
            const int   myi = s_idx[tid];
            int rank = 0;
            for (int j = 0; j < cnt; ++j) {
                const float vj = s_val[j];
                const int   ij = s_idx[j];
                rank += (vj > myv) || (vj == myv && ij < myi);
            }
            if (rank < KSEL) { s_sel_idx[rank] = myi; s_sel_v[rank] = myv; }
        }
        __syncthreads();
    } else {
        // Exact fallback (rare/never): 16 rounds of bounded block-argmax over the
        // row (values still live in v[8] registers).
        if (tid == 0) s_bound = ~0ull;
        __syncthreads();
        for (int round = 0; round < KSEL; ++round) {
            const unsigned long long bound = s_bound;
            unsigned long long best = 0ull;
#pragma unroll
            for (int j = 0; j < 8; ++j) {
                const int base = (j * 256 + tid) * 4;
                unsigned long long k0 = make_key(v[j].x, base + 0);
                unsigned long long k1 = make_key(v[j].y, base + 1);
                unsigned long long k2 = make_key(v[j].z, base + 2);
                unsigned long long k3 = make_key(v[j].w, base + 3);
                if (k0 < bound && k0 > best) best = k0;
                if (k1 < bound && k1 > best) best = k1;
                if (k2 < bound && k2 > best) best = k2;
                if (k3 < bound && k3 > best) best = k3;
            }
            s_red[tid] = best;
            __syncthreads();
            for (int s = 128; s > 0; s >>= 1) {
                if (tid < s && s_red[tid + s] > s_red[tid]) s_red[tid] = s_red[tid + s];
                __syncthreads();
            }
            if (tid == 0) {
                const unsigned long long bk = s_red[0];
                const unsigned u    = (unsigned)(bk >> 32);
                const unsigned bits = (u & 0x80000000u) ? (u & 0x7FFFFFFFu) : ~u;
                s_sel_v[round]   = __uint_as_float(bits);
                s_sel_idx[round] = (int)(0xFFFFFFFFu - (unsigned)(bk & 0xFFFFFFFFu));
                s_bound = bk;
            }
            __syncthreads();
        }
    }

    // Softmax numerators over the selected 16 (rank 0 holds the row max).
    if (tid < KSEL) {
        const float m = s_sel_v[0];
        s_sel_e[tid] = expf(s_sel_v[tid] - m);
    }
    __syncthreads();

    float ssum = 0.f;
#pragma unroll
    for (int k = 0; k < KSEL; ++k) ssum += s_sel_e[k];

    // Weighted gather of h rows: 4 waves x 4 neighbors, 64 features per lane.
    const int f = tid & 63;
    const int g = tid >> 6;
    float acc = 0.f;
#pragma unroll
    for (int k = 0; k < 4; ++k) {
        const int kk = g * 4 + k;
        acc += s_sel_e[kk] * h[(size_t)s_sel_idx[kk] * F_OUT + f];
    }
    s_part[g][f] = acc;
    __syncthreads();

    if (g == 0) {
        const float tot = (s_part[0][f] + s_part[1][f] + s_part[2][f] + s_part[3][f]) / ssum;
        const int c = r >> 13;          // r / N_V
        const int n = r & (N_V - 1);    // r % N_V
        out[(size_t)n * (CC * F_OUT) + c * F_OUT + f] = tot;
    }
}

extern "C" void kernel_launch(void* const* d_in, const int* in_sizes, int n_in,
                              void* d_out, int out_size, void* d_ws, size_t ws_size,
                              hipStream_t stream) {
    const float* x   = (const float*)d_in[0];  // [8192, 512]
    const float* W   = (const float*)d_in[1];  // [512, 64]
    const float* att = (const float*)d_in[2];  // [32768, 8192]
    float*       out = (float*)d_out;          // [8192, 256]
    float*       h   = (float*)d_ws;           // scratch: [8192, 64] fp32 = 2 MB

    linear_kernel<<<N_V / 16, 256, 0, stream>>>(x, W, h);
    topk_spmm_kernel<<<N_V * CC, 256, 0, stream>>>(att, h, out);
}